// Round 5
// baseline (188.678 us; speedup 1.0000x reference)
//
#include <hip/hip_runtime.h>
#include <math.h>

#define SEQ   2048
#define HDIM  1024
#define NH    16
#define DH    64
#define MTOT  4096   // B*S
#define BHTOT 32     // B*NH

typedef _Float16 half_t;
typedef __attribute__((ext_vector_type(2))) __fp16 fp16x2;
typedef __attribute__((ext_vector_type(4))) _Float16 half4;
typedef __attribute__((ext_vector_type(8))) _Float16 half8;
typedef __attribute__((ext_vector_type(4))) float float4v;

// async global->LDS DMA, 16 B per lane; LDS dest = wave-uniform base + lane*16
typedef __attribute__((address_space(1))) const unsigned int guint;
typedef __attribute__((address_space(3))) unsigned int luint;
__device__ __forceinline__ void glds16(const half_t* g, half_t* l) {
    __builtin_amdgcn_global_load_lds((guint*)g, (luint*)l, 16, 0, 0);
}

// ---------------- fused prologue: 5 fp32->fp16 casts + rope table ----------------
__global__ __launch_bounds__(256)
void prep(const float* __restrict__ x,  const float* __restrict__ wq,
          const float* __restrict__ wk, const float* __restrict__ wv,
          const float* __restrict__ wo,
          half_t* __restrict__ xh,  half_t* __restrict__ wqh,
          half_t* __restrict__ wkh, half_t* __restrict__ wvh,
          half_t* __restrict__ woh, float2* __restrict__ rope)
{
    const int bid = blockIdx.x;
    if (bid < 8192) {
        int i = bid * 256 + threadIdx.x;
        const float* s; half_t* d;
        if (i < 1048576) { s = x; d = xh; }
        else {
            int j = i - 1048576;
            int w = j >> 18; i = j & 262143;
            s = (w == 0) ? wq : (w == 1) ? wk : (w == 2) ? wv : wo;
            d = (w == 0) ? wqh : (w == 1) ? wkh : (w == 2) ? wvh : woh;
        }
        float4 v = ((const float4*)s)[i];
        union { half_t h[4]; uint2 u; } tmp;
        tmp.h[0] = (half_t)v.x; tmp.h[1] = (half_t)v.y;
        tmp.h[2] = (half_t)v.z; tmp.h[3] = (half_t)v.w;
        ((uint2*)d)[i] = tmp.u;
    } else {
        int tt = (bid - 8192) * 256 + threadIdx.x;   // 0 .. SEQ*32-1
        int s = tt >> 5, j = tt & 31;
        float inv = powf(10000.0f, -(float)j / 32.0f);
        float ang = (float)s * inv;
        rope[tt] = make_float2(cosf(ang), sinf(ang));
    }
}

// ---------------- GEMM: QKV only. C = A(4096x1024,f16) * W^T, 128x128 tiles ----
// BK=64, line-local XOR swizzle, 5 blocks/CU. (unchanged from r4 — verified)
__global__ __launch_bounds__(256, 5)
void gemm_qkv(const half_t* __restrict__ A,
              const half_t* __restrict__ w0, const half_t* __restrict__ w1,
              const half_t* __restrict__ w2,
              half_t* __restrict__ Qb, half_t* __restrict__ Kb,
              half_t* __restrict__ Vtb,
              const float2* __restrict__ rope)
{
    const int mode = blockIdx.z;
    const half_t* Bw = (mode == 1) ? w1 : (mode == 2) ? w2 : w0;

    __shared__ __align__(16) half_t Tsh[2][128][64];   // A tile | B tile, 32 KB
    half_t (*Ash)[64] = Tsh[0];
    half_t (*Bsh)[64] = Tsh[1];

    const int t    = threadIdx.x;
    const int lane = t & 63;
    const int wave = t >> 6;
    const int quad = lane >> 4;
    const int l16  = lane & 15;
    const int wr   = (wave >> 1) * 64;
    const int wc   = (wave & 1) * 64;
    const int bm   = blockIdx.x, bn = blockIdx.y;

    const int srow   = lane >> 3;               // 0..7 within an 8-row DMA chunk
    const int schunk = (lane & 7) ^ (srow & 3); // line-local pre-swizzle
    const half_t* Asrc = A  + (size_t)(bm * 128 + srow) * HDIM + schunk * 8;
    const half_t* Bsrc = Bw + (size_t)(bn * 128 + srow) * HDIM + schunk * 8;
    const int swz = (l16 & 3) << 4;             // read-side XOR (byte offset)

    float4v acc[4][4] = {};

    for (int kt = 0; kt < HDIM / 64; ++kt) {
        const half_t* Ak = Asrc + kt * 64;
        const half_t* Bk = Bsrc + kt * 64;
#pragma unroll
        for (int c = 0; c < 4; ++c) {
            const int r8 = wave * 32 + c * 8;
            glds16(Ak + (size_t)r8 * HDIM, &Ash[r8][0]);
            glds16(Bk + (size_t)r8 * HDIM, &Bsh[r8][0]);
        }
        __syncthreads();
#pragma unroll
        for (int kk = 0; kk < 2; ++kk) {
            const int cb = ((quad << 4) | (kk << 6)) ^ swz;
            half8 af[4], bf[4];
#pragma unroll
            for (int mb = 0; mb < 4; ++mb)
                af[mb] = *(const half8*)((const char*)&Ash[wr + mb * 16 + l16][0] + cb);
#pragma unroll
            for (int nb = 0; nb < 4; ++nb)
                bf[nb] = *(const half8*)((const char*)&Bsh[wc + nb * 16 + l16][0] + cb);
#pragma unroll
            for (int mb = 0; mb < 4; ++mb)
#pragma unroll
                for (int nb = 0; nb < 4; ++nb)
                    acc[mb][nb] = __builtin_amdgcn_mfma_f32_16x16x32_f16(af[mb], bf[nb], acc[mb][nb], 0, 0, 0);
        }
        __syncthreads();
    }

    if (mode == 2) {  // V, transposed store: Vtb[bh][d][s]
#pragma unroll
        for (int mb = 0; mb < 4; ++mb)
#pragma unroll
            for (int nb = 0; nb < 4; ++nb) {
                int row0 = bm * 128 + wr + mb * 16 + quad * 4;
                int col  = bn * 128 + wc + nb * 16 + l16;
                int b = row0 >> 11, s0 = row0 & 2047;
                int h = col >> 6,  dd = col & 63;
                union { half_t h4[4]; uint2 u; } tmp;
#pragma unroll
                for (int r = 0; r < 4; ++r) tmp.h4[r] = (half_t)acc[mb][nb][r];
                *(uint2*)&Vtb[((size_t)((b * NH + h) * DH + dd)) * SEQ + s0] = tmp.u;
            }
        return;
    }
    // mode 0 (Q: rope + scale) / mode 1 (K: rope)
    {
        half_t* Ob = (mode == 0) ? Qb : Kb;
        const float scl = (mode == 0) ? 0.125f * 1.44269504088896f : 1.0f;
        const int h = (bn * 128 + wc) >> 6;   // wave's 64 cols = one head
        float* E = (float*)&Tsh[0][0][0] + wave * 1088;
#pragma unroll
        for (int mb = 0; mb < 4; ++mb) {
#pragma unroll
            for (int nb = 0; nb < 4; ++nb)
#pragma unroll
                for (int r = 0; r < 4; ++r)
                    E[(quad * 4 + r) * 68 + nb * 16 + l16] = acc[mb][nb][r];
            __asm__ volatile("s_waitcnt lgkmcnt(0)" ::: "memory");  // wave-private region
#pragma unroll
            for (int c = 0; c < 2; ++c) {
                const int uidx = c * 64 + lane;
                const int row = uidx >> 3, ch = uidx & 7;
                const int sg = bm * 128 + wr + mb * 16 + row;
                const int b = sg >> 11, s = sg & 2047;
                const float* Er = E + row * 68 + ch * 8;
                const float4 e0 = *(const float4*)Er;
                const float4 e1 = *(const float4*)(Er + 4);
                const float4* rp = (const float4*)(rope + (size_t)s * 32 + ch * 4);
                const float4 r01 = rp[0];   // cos0,sin0,cos1,sin1
                const float4 r23 = rp[1];
                union { half_t hh[8]; uint4 u; } o;
                o.hh[0] = (half_t)((e0.x * r01.x - e0.y * r01.y) * scl);
                o.hh[1] = (half_t)((e0.x * r01.y + e0.y * r01.x) * scl);
                o.hh[2] = (half_t)((e0.z * r01.z - e0.w * r01.w) * scl);
                o.hh[3] = (half_t)((e0.z * r01.w + e0.w * r01.z) * scl);
                o.hh[4] = (half_t)((e1.x * r23.x - e1.y * r23.y) * scl);
                o.hh[5] = (half_t)((e1.x * r23.y + e1.y * r23.x) * scl);
                o.hh[6] = (half_t)((e1.z * r23.z - e1.w * r23.w) * scl);
                o.hh[7] = (half_t)((e1.z * r23.w + e1.w * r23.z) * scl);
                *(uint4*)&Ob[((size_t)((b * NH + h) * SEQ + s)) * DH + ch * 8] = o.u;
            }
        }
    }
}

// ---------------- output GEMM: out(f32) = ah(4096x1024,f16) @ wo^T ----------------
// v3: 2-phase double-buffer with counted vmcnt + raw s_barrier: stage(t+1) is
// issued BEFORE compute(t), so its L2/HBM latency hides under the MFMAs; the
// end-of-iter wait+barrier replaces __syncthreads' stage->drain->compute
// pattern that exposed full latency every iteration. LDS 48 KB, 2 blocks/CU.
__global__ __launch_bounds__(256)
void gemm_out(const half_t* __restrict__ A, const half_t* __restrict__ W,
              float* __restrict__ outF)
{
    __shared__ __align__(16) half_t Ash[2][64][64];    // 16 KB
    __shared__ __align__(16) half_t Bsh[2][128][64];   // 32 KB

    const int t    = threadIdx.x;
    const int lane = t & 63;
    const int wave = t >> 6;
    const int quad = lane >> 4;
    const int l16  = lane & 15;
    const int wr   = (wave >> 1) * 32;   // M offset within tile
    const int wc   = (wave & 1) * 64;    // N offset
    const int bm   = blockIdx.x, bn = blockIdx.y;

    const int srow   = lane >> 3;
    const int schunk = (lane & 7) ^ (srow & 3);
    const half_t* Asrc = A + (size_t)(bm * 64  + srow) * HDIM + schunk * 8;
    const half_t* Bsrc = W + (size_t)(bn * 128 + srow) * HDIM + schunk * 8;
    const int swz = (l16 & 3) << 4;

    auto stage = [&](int kt, int buf) {
        const half_t* Ak = Asrc + kt * 64;
        const half_t* Bk = Bsrc + kt * 64;
#pragma unroll
        for (int c = 0; c < 2; ++c) {
            const int r8 = wave * 16 + c * 8;
            glds16(Ak + (size_t)r8 * HDIM, &Ash[buf][r8][0]);
        }
#pragma unroll
        for (int c = 0; c < 4; ++c) {
            const int r8 = wave * 32 + c * 8;
            glds16(Bk + (size_t)r8 * HDIM, &Bsh[buf][r8][0]);
        }
    };

    float4v acc[2][4] = {};

    stage(0, 0);
    __asm__ volatile("s_waitcnt vmcnt(0)" ::: "memory");
    __builtin_amdgcn_s_barrier();
    __builtin_amdgcn_sched_barrier(0);

    for (int kt = 0; kt < HDIM / 64; ++kt) {
        const int cur = kt & 1, nxt = cur ^ 1;
        if (kt + 1 < HDIM / 64) stage(kt + 1, nxt);   // prefetch under compute
#pragma unroll
        for (int kk = 0; kk < 2; ++kk) {
            const int cb = ((quad << 4) | (kk << 6)) ^ swz;
            half8 af[2], bf[4];
#pragma unroll
            for (int mb = 0; mb < 2; ++mb)
                af[mb] = *(const half8*)((const char*)&Ash[cur][wr + mb * 16 + l16][0] + cb);
#pragma unroll
            for (int nb = 0; nb < 4; ++nb)
                bf[nb] = *(const half8*)((const char*)&Bsh[cur][wc + nb * 16 + l16][0] + cb);
#pragma unroll
            for (int mb = 0; mb < 2; ++mb)
#pragma unroll
                for (int nb = 0; nb < 4; ++nb)
                    acc[mb][nb] = __builtin_amdgcn_mfma_f32_16x16x32_f16(af[mb], bf[nb], acc[mb][nb], 0, 0, 0);
        }
        __asm__ volatile("s_waitcnt vmcnt(0)" ::: "memory");  // next tile landed
        __builtin_amdgcn_s_barrier();
        __builtin_amdgcn_sched_barrier(0);
    }

#pragma unroll
    for (int mb = 0; mb < 2; ++mb)
#pragma unroll
        for (int nb = 0; nb < 4; ++nb) {
            int row0 = bm * 64 + wr + mb * 16 + quad * 4;
            int col  = bn * 128 + wc + nb * 16 + l16;
#pragma unroll
            for (int r = 0; r < 4; ++r)
                outF[(size_t)(row0 + r) * HDIM + col] = acc[mb][nb][r];
        }
}

// ---------------- fused attention ----------------
// Reference semantics: softmax over ALL keys, THEN causal zeroing, NO renorm.
// v5 on top of r4's structure (512 thr, 2 blocks/CU, 1 q-group/wave):
//  (a) K prefetch depth 2: Ksh[3] ring, glds16 K(t+2) issued at iter t; raw
//      s_barrier + counted s_waitcnt vmcnt(1) (leaves K(t+2) in flight) —
//      replaces __syncthreads' vmcnt(0) drain of the just-issued DMA.
//      V register-load is NOT manually counted: the compiler's exact auto-wait
//      before its ds_write makes the manual K count robust to load reordering.
//  (b) Vsh chunk-swizzle [64][64] (store chunk c at c^(row&7), read with same
//      involution): PV 8B reads go from 8 words/bank (even banks only) to the
//      4-word hardware minimum; stores stay minimal. -2.25 KB LDS.
__global__ __launch_bounds__(512, 4)
void attn_fused(const half_t* __restrict__ Qb, const half_t* __restrict__ Kb,
                const half_t* __restrict__ Vtb, half_t* __restrict__ AOut)
{
    const int bx = blockIdx.x;   // 0..15
    const int p  = bx >> 1;      // q-tile pair (p, 15-p), p in 0..7
    const int hf = bx & 1;       // which 64-row half of each tile
    const int bh = blockIdx.y;   // 0..31 (b*16+h)
    const int NT = SEQ / 64;     // 32

    __shared__ __align__(16) half_t Ksh[3][64][64];   // ring, chunk-swizzled src
    __shared__ __align__(16) half_t Vsh[2][64][64];   // [buf][d][key], chunk-swizzled

    const int t = threadIdx.x;
    const int wave = t >> 6, lane = t & 63, quad = lane >> 4, l16 = lane & 15;
    const int heavy = wave >> 2, wl = wave & 3;
    const int qtile = heavy ? (15 - p) : p;
    const int q0 = qtile * 128 + hf * 64 + wl * 16;   // wave's 16 q rows
    const int ktop = 2 * (15 - p) + hf;               // V staging bound

    // Q fragment (B-operand layout of 16x16x32)
    const half_t* Qp = Qb + ((size_t)bh * SEQ + q0 + l16) * DH + quad * 8;
    const half8 qf0 = *(const half8*)Qp;
    const half8 qf1 = *(const half8*)(Qp + 32);

    float4v o[4] = {};     // O^T accum
    float4v ls = {};       // 4 independent denominator chains

    // K DMA staging: wave stages rows wave*8 .. wave*8+7 (XOR chunk swizzle)
    const int krow = lane >> 3, kpos = lane & 7;
    const int kchunk = kpos ^ krow;
    const half_t* Ksrc = Kb + ((size_t)bh * SEQ + wave * 8 + krow) * DH + kchunk * 8;
    const int ko1 = ((quad ^ (l16 & 7)) * 8);
    const int ko2 = ko1 ^ 32;

    // V staging: 512 threads x 1 uint4 = 64x64 tile; chunk-swizzled store
    const int sr  = t >> 3;                     // 0..63 (d)
    const int svc = ((t & 7) ^ (sr & 7)) * 8;   // swizzled chunk (halves)
    const half_t* Vg = Vtb + ((size_t)bh * DH + sr) * SEQ + (t & 7) * 8;
    const int vxo = l16 & 7;                    // read-side row XOR
    const int vro = (quad & 1) * 8;             // byte offset within 16B chunk

    // prologue: V(0) + K(0) + K(1)
    uint4 va = *(const uint4*)(Vg);
    glds16(Ksrc,                   &Ksh[0][wave * 8][0]);
    glds16(Ksrc + (size_t)64 * DH, &Ksh[1][wave * 8][0]);
    *(uint4*)&Vsh[0][sr][svc] = va;                       // compiler waits va
    __asm__ volatile("s_waitcnt vmcnt(1)" ::: "memory");  // K(0) done, K(1) flying
    __asm__ volatile("s_waitcnt lgkmcnt(0)" ::: "memory");
    __builtin_amdgcn_s_barrier();
    __builtin_amdgcn_sched_barrier(0);

    int i0 = 0, i1 = 1, i2 = 2;   // Ksh ring: cur, next, stage-target
    for (int kt = 0; kt < NT; ++kt) {
        const int curv = kt & 1, nxtv = curv ^ 1;
        const bool vnext = (kt + 1 <= ktop) && (kt + 1 < NT);
        const bool knext = (kt + 2 < NT);

        if (vnext) va = *(const uint4*)(Vg + (kt + 1) * 64);
        if (knext)
            glds16(Ksrc + (size_t)(kt + 2) * 64 * DH, &Ksh[i2][wave * 8][0]);

        // S^T = K * Q^T
        float4v sc[4];
        __builtin_amdgcn_s_setprio(1);
#pragma unroll
        for (int nb = 0; nb < 4; ++nb) {
            const half_t* kp = &Ksh[i0][nb * 16 + l16][0];
            half8 kf0 = *(const half8*)(kp + ko1);
            half8 kf1 = *(const half8*)(kp + ko2);
            float4v a = {};
            a = __builtin_amdgcn_mfma_f32_16x16x32_f16(kf0, qf0, a, 0, 0, 0);
            a = __builtin_amdgcn_mfma_f32_16x16x32_f16(kf1, qf1, a, 0, 0, 0);
            sc[nb] = a;
        }
        __builtin_amdgcn_s_setprio(0);

        // P = exp2(sc); 4 independent partial-denominator chains
#pragma unroll
        for (int nb = 0; nb < 4; ++nb)
#pragma unroll
            for (int r = 0; r < 4; ++r) {
                float e = __builtin_amdgcn_exp2f(sc[nb][r]);
                sc[nb][r] = e;
                ls[r] += e;
            }

        const int kbase = kt * 64;
        if (kbase <= q0 + 15) {   // wave-uniform: at least one unmasked key
            if (kbase + 63 > q0) {   // straddle: element-wise post-softmax zeroing
                int qg = q0 + l16;
#pragma unroll
                for (int nb = 0; nb < 4; ++nb)
#pragma unroll
                    for (int r = 0; r < 4; ++r)
                        if (kbase + nb * 16 + quad * 4 + r > qg) sc[nb][r] = 0.f;
            }
            half4 pf[4];
#pragma unroll
            for (int nb = 0; nb < 4; ++nb) {
                union { fp16x2 v2[2]; half4 v4; } u;
                u.v2[0] = __builtin_amdgcn_cvt_pkrtz(sc[nb][0], sc[nb][1]);
                u.v2[1] = __builtin_amdgcn_cvt_pkrtz(sc[nb][2], sc[nb][3]);
                pf[nb] = u.v4;
            }
            __builtin_amdgcn_s_setprio(1);
#pragma unroll
            for (int md = 0; md < 4; ++md) {
                const char* vrow = (const char*)&Vsh[curv][md * 16 + l16][0];
#pragma unroll
                for (int nb = 0; nb < 4; ++nb) {
                    const int sco = (((nb * 2 + (quad >> 1)) ^ vxo) << 4) + vro;
                    half4 vf = *(const half4*)(vrow + sco);
                    o[md] = __builtin_amdgcn_mfma_f32_16x16x16f16(vf, pf[nb], o[md], 0, 0, 0);
                }
            }
            __builtin_amdgcn_s_setprio(0);
        }

        if (vnext) *(uint4*)&Vsh[nxtv][sr][svc] = va;     // compiler waits va
        if (knext) { __asm__ volatile("s_waitcnt vmcnt(1)" ::: "memory"); }
        else       { __asm__ volatile("s_waitcnt vmcnt(0)" ::: "memory"); }
        __asm__ volatile("s_waitcnt lgkmcnt(0)" ::: "memory");
        __builtin_amdgcn_s_barrier();
        __builtin_amdgcn_sched_barrier(0);
        const int tmp = i0; i0 = i1; i1 = i2; i2 = tmp;
    }

    // epilogue: denominator (2 shuffles) + O^T transpose via per-wave LDS scratch.
    const int b = bh >> 4, h = bh & 15;
    const int orow = lane >> 2, occ = (lane & 3) * 16;
    half_t* scr = (heavy ? (half_t*)Vsh : (half_t*)Ksh) + wl * 1152;
    half_t (*Osh)[72] = (half_t(*)[72])scr;   // 16 x 72
    {
        float rs = (ls[0] + ls[1]) + (ls[2] + ls[3]);
        rs += __shfl_xor(rs, 16, 64);
        rs += __shfl_xor(rs, 32, 64);
        const float inv = 1.0f / rs;
#pragma unroll
        for (int md = 0; md < 4; ++md)
#pragma unroll
            for (int r = 0; r < 4; ++r)
                Osh[l16][md * 16 + quad * 4 + r] = (half_t)(o[md][r] * inv);
        __asm__ volatile("s_waitcnt lgkmcnt(0)" ::: "memory");
        uint4 o0 = *(const uint4*)&Osh[orow][occ];
        uint4 o1 = *(const uint4*)&Osh[orow][occ + 8];
        const int s = q0 + orow;
        half_t* dst = AOut + ((size_t)(b * SEQ + s)) * HDIM + h * DH + occ;
        *(uint4*)dst       = o0;
        *(uint4*)(dst + 8) = o1;
    }
}

// ---------------- launch ----------------
extern "C" void kernel_launch(void* const* d_in, const int* in_sizes, int n_in,
                              void* d_out, int out_size, void* d_ws, size_t ws_size,
                              hipStream_t stream)
{
    const float* x  = (const float*)d_in[0];
    const float* wq = (const float*)d_in[1];
    const float* wk = (const float*)d_in[2];
    const float* wv = (const float*)d_in[3];
    const float* wo = (const float*)d_in[4];
    float* out = (float*)d_out;

    char* ws = (char*)d_ws;
    size_t off = 0;
    auto alloc = [&](size_t bytes) -> void* {
        void* p = ws + off;
        off += (bytes + 255) & ~(size_t)255;
        return p;
    };
    half_t* xh   = (half_t*)alloc((size_t)MTOT * HDIM * 2);   // 8 MB
    half_t* wqh  = (half_t*)alloc((size_t)HDIM * HDIM * 2);   // 2 MB
    half_t* wkh  = (half_t*)alloc((size_t)HDIM * HDIM * 2);
    half_t* wvh  = (half_t*)alloc((size_t)HDIM * HDIM * 2);
    half_t* woh  = (half_t*)alloc((size_t)HDIM * HDIM * 2);
    half_t* Qb   = (half_t*)alloc((size_t)BHTOT * SEQ * DH * 2);  // 8 MB
    half_t* Kb   = (half_t*)alloc((size_t)BHTOT * SEQ * DH * 2);
    half_t* Vtb  = (half_t*)alloc((size_t)BHTOT * SEQ * DH * 2);
    half_t* ah   = (half_t*)alloc((size_t)MTOT * HDIM * 2);       // 8 MB
    float2* rope = (float2*)alloc((size_t)SEQ * 32 * sizeof(float2));

    prep<<<8448, 256, 0, stream>>>(x, wq, wk, wv, wo, xh, wqh, wkh, wvh, woh, rope);

    // Q, K, V in one launch (grid.z selects weight + epilogue)
    gemm_qkv<<<dim3(32, 8, 3), 256, 0, stream>>>(xh, wqh, wkh, wvh,
                                                 Qb, Kb, Vtb, rope);
    // attn: 512-thread blocks, 512 blocks = 2 blocks/CU = 4 waves/SIMD
    attn_fused<<<dim3(16, 32), 512, 0, stream>>>(Qb, Kb, Vtb, ah);
    // out = attn @ w_o^T: 64x128 tiles, 2-phase pipelined
    gemm_out<<<dim3(64, 8), 256, 0, stream>>>(ah, woh, out);
}

// Round 6
// 186.303 us; speedup vs baseline: 1.0127x; 1.0127x over previous
//
#include <hip/hip_runtime.h>
#include <math.h>

#define SEQ   2048
#define HDIM  1024
#define NH    16
#define DH    64
#define MTOT  4096   // B*S
#define BHTOT 32     // B*NH

typedef _Float16 half_t;
typedef __attribute__((ext_vector_type(2))) __fp16 fp16x2;
typedef __attribute__((ext_vector_type(4))) _Float16 half4;
typedef __attribute__((ext_vector_type(8))) _Float16 half8;
typedef __attribute__((ext_vector_type(4))) float float4v;

// async global->LDS DMA, 16 B per lane; LDS dest = wave-uniform base + lane*16
typedef __attribute__((address_space(1))) const unsigned int guint;
typedef __attribute__((address_space(3))) unsigned int luint;
__device__ __forceinline__ void glds16(const half_t* g, half_t* l) {
    __builtin_amdgcn_global_load_lds((guint*)g, (luint*)l, 16, 0, 0);
}

// ---------------- fused prologue: 5 fp32->fp16 casts + rope table ----------------
__global__ __launch_bounds__(256)
void prep(const float* __restrict__ x,  const float* __restrict__ wq,
          const float* __restrict__ wk, const float* __restrict__ wv,
          const float* __restrict__ wo,
          half_t* __restrict__ xh,  half_t* __restrict__ wqh,
          half_t* __restrict__ wkh, half_t* __restrict__ wvh,
          half_t* __restrict__ woh, float2* __restrict__ rope)
{
    const int bid = blockIdx.x;
    if (bid < 8192) {
        int i = bid * 256 + threadIdx.x;
        const float* s; half_t* d;
        if (i < 1048576) { s = x; d = xh; }
        else {
            int j = i - 1048576;
            int w = j >> 18; i = j & 262143;
            s = (w == 0) ? wq : (w == 1) ? wk : (w == 2) ? wv : wo;
            d = (w == 0) ? wqh : (w == 1) ? wkh : (w == 2) ? wvh : woh;
        }
        float4 v = ((const float4*)s)[i];
        union { half_t h[4]; uint2 u; } tmp;
        tmp.h[0] = (half_t)v.x; tmp.h[1] = (half_t)v.y;
        tmp.h[2] = (half_t)v.z; tmp.h[3] = (half_t)v.w;
        ((uint2*)d)[i] = tmp.u;
    } else {
        int tt = (bid - 8192) * 256 + threadIdx.x;   // 0 .. SEQ*32-1
        int s = tt >> 5, j = tt & 31;
        float inv = powf(10000.0f, -(float)j / 32.0f);
        float ang = (float)s * inv;
        rope[tt] = make_float2(cosf(ang), sinf(ang));
    }
}

// ---------------- GEMM: QKV only. C = A(4096x1024,f16) * W^T, 128x128 tiles ----
// BK=64, line-local XOR swizzle, 5 blocks/CU. (unchanged — verified)
__global__ __launch_bounds__(256, 5)
void gemm_qkv(const half_t* __restrict__ A,
              const half_t* __restrict__ w0, const half_t* __restrict__ w1,
              const half_t* __restrict__ w2,
              half_t* __restrict__ Qb, half_t* __restrict__ Kb,
              half_t* __restrict__ Vtb,
              const float2* __restrict__ rope)
{
    const int mode = blockIdx.z;
    const half_t* Bw = (mode == 1) ? w1 : (mode == 2) ? w2 : w0;

    __shared__ __align__(16) half_t Tsh[2][128][64];   // A tile | B tile, 32 KB
    half_t (*Ash)[64] = Tsh[0];
    half_t (*Bsh)[64] = Tsh[1];

    const int t    = threadIdx.x;
    const int lane = t & 63;
    const int wave = t >> 6;
    const int quad = lane >> 4;
    const int l16  = lane & 15;
    const int wr   = (wave >> 1) * 64;
    const int wc   = (wave & 1) * 64;
    const int bm   = blockIdx.x, bn = blockIdx.y;

    const int srow   = lane >> 3;               // 0..7 within an 8-row DMA chunk
    const int schunk = (lane & 7) ^ (srow & 3); // line-local pre-swizzle
    const half_t* Asrc = A  + (size_t)(bm * 128 + srow) * HDIM + schunk * 8;
    const half_t* Bsrc = Bw + (size_t)(bn * 128 + srow) * HDIM + schunk * 8;
    const int swz = (l16 & 3) << 4;             // read-side XOR (byte offset)

    float4v acc[4][4] = {};

    for (int kt = 0; kt < HDIM / 64; ++kt) {
        const half_t* Ak = Asrc + kt * 64;
        const half_t* Bk = Bsrc + kt * 64;
#pragma unroll
        for (int c = 0; c < 4; ++c) {
            const int r8 = wave * 32 + c * 8;
            glds16(Ak + (size_t)r8 * HDIM, &Ash[r8][0]);
            glds16(Bk + (size_t)r8 * HDIM, &Bsh[r8][0]);
        }
        __syncthreads();
#pragma unroll
        for (int kk = 0; kk < 2; ++kk) {
            const int cb = ((quad << 4) | (kk << 6)) ^ swz;
            half8 af[4], bf[4];
#pragma unroll
            for (int mb = 0; mb < 4; ++mb)
                af[mb] = *(const half8*)((const char*)&Ash[wr + mb * 16 + l16][0] + cb);
#pragma unroll
            for (int nb = 0; nb < 4; ++nb)
                bf[nb] = *(const half8*)((const char*)&Bsh[wc + nb * 16 + l16][0] + cb);
#pragma unroll
            for (int mb = 0; mb < 4; ++mb)
#pragma unroll
                for (int nb = 0; nb < 4; ++nb)
                    acc[mb][nb] = __builtin_amdgcn_mfma_f32_16x16x32_f16(af[mb], bf[nb], acc[mb][nb], 0, 0, 0);
        }
        __syncthreads();
    }

    if (mode == 2) {  // V, transposed store: Vtb[bh][d][s]
#pragma unroll
        for (int mb = 0; mb < 4; ++mb)
#pragma unroll
            for (int nb = 0; nb < 4; ++nb) {
                int row0 = bm * 128 + wr + mb * 16 + quad * 4;
                int col  = bn * 128 + wc + nb * 16 + l16;
                int b = row0 >> 11, s0 = row0 & 2047;
                int h = col >> 6,  dd = col & 63;
                union { half_t h4[4]; uint2 u; } tmp;
#pragma unroll
                for (int r = 0; r < 4; ++r) tmp.h4[r] = (half_t)acc[mb][nb][r];
                *(uint2*)&Vtb[((size_t)((b * NH + h) * DH + dd)) * SEQ + s0] = tmp.u;
            }
        return;
    }
    // mode 0 (Q: rope + scale) / mode 1 (K: rope)
    {
        half_t* Ob = (mode == 0) ? Qb : Kb;
        const float scl = (mode == 0) ? 0.125f * 1.44269504088896f : 1.0f;
        const int h = (bn * 128 + wc) >> 6;   // wave's 64 cols = one head
        float* E = (float*)&Tsh[0][0][0] + wave * 1088;
#pragma unroll
        for (int mb = 0; mb < 4; ++mb) {
#pragma unroll
            for (int nb = 0; nb < 4; ++nb)
#pragma unroll
                for (int r = 0; r < 4; ++r)
                    E[(quad * 4 + r) * 68 + nb * 16 + l16] = acc[mb][nb][r];
            __asm__ volatile("s_waitcnt lgkmcnt(0)" ::: "memory");  // wave-private region
#pragma unroll
            for (int c = 0; c < 2; ++c) {
                const int uidx = c * 64 + lane;
                const int row = uidx >> 3, ch = uidx & 7;
                const int sg = bm * 128 + wr + mb * 16 + row;
                const int b = sg >> 11, s = sg & 2047;
                const float* Er = E + row * 68 + ch * 8;
                const float4 e0 = *(const float4*)Er;
                const float4 e1 = *(const float4*)(Er + 4);
                const float4* rp = (const float4*)(rope + (size_t)s * 32 + ch * 4);
                const float4 r01 = rp[0];   // cos0,sin0,cos1,sin1
                const float4 r23 = rp[1];
                union { half_t hh[8]; uint4 u; } o;
                o.hh[0] = (half_t)((e0.x * r01.x - e0.y * r01.y) * scl);
                o.hh[1] = (half_t)((e0.x * r01.y + e0.y * r01.x) * scl);
                o.hh[2] = (half_t)((e0.z * r01.z - e0.w * r01.w) * scl);
                o.hh[3] = (half_t)((e0.z * r01.w + e0.w * r01.z) * scl);
                o.hh[4] = (half_t)((e1.x * r23.x - e1.y * r23.y) * scl);
                o.hh[5] = (half_t)((e1.x * r23.y + e1.y * r23.x) * scl);
                o.hh[6] = (half_t)((e1.z * r23.z - e1.w * r23.w) * scl);
                o.hh[7] = (half_t)((e1.z * r23.w + e1.w * r23.z) * scl);
                *(uint4*)&Ob[((size_t)((b * NH + h) * SEQ + s)) * DH + ch * 8] = o.u;
            }
        }
    }
}

// ---------------- output GEMM: out(f32) = ah(4096x1024,f16) @ wo^T ----------------
// v4: 64x64 tiles -> grid (64,16) = 1024 blocks = 4 blocks/CU (LDS 32 KB dbuf,
// tiny acc): doubles the wave pool of this latency-bound kernel. 2-phase
// prefetch loop (stage(t+1) before compute(t)) kept from r5.
__global__ __launch_bounds__(256)
void gemm_out(const half_t* __restrict__ A, const half_t* __restrict__ W,
              float* __restrict__ outF)
{
    __shared__ __align__(16) half_t Ash[2][64][64];    // 16 KB
    __shared__ __align__(16) half_t Bsh[2][64][64];    // 16 KB

    const int t    = threadIdx.x;
    const int lane = t & 63;
    const int wave = t >> 6;
    const int quad = lane >> 4;
    const int l16  = lane & 15;
    const int wr   = (wave >> 1) * 32;   // M offset within tile
    const int wc   = (wave & 1) * 32;    // N offset
    const int bm   = blockIdx.x, bn = blockIdx.y;

    const int srow   = lane >> 3;
    const int schunk = (lane & 7) ^ (srow & 3);
    const half_t* Asrc = A + (size_t)(bm * 64 + srow) * HDIM + schunk * 8;
    const half_t* Bsrc = W + (size_t)(bn * 64 + srow) * HDIM + schunk * 8;
    const int swz = (l16 & 3) << 4;

    auto stage = [&](int kt, int buf) {
        const half_t* Ak = Asrc + kt * 64;
        const half_t* Bk = Bsrc + kt * 64;
#pragma unroll
        for (int c = 0; c < 2; ++c) {
            const int r8 = wave * 16 + c * 8;
            glds16(Ak + (size_t)r8 * HDIM, &Ash[buf][r8][0]);
            glds16(Bk + (size_t)r8 * HDIM, &Bsh[buf][r8][0]);
        }
    };

    float4v acc[2][2] = {};

    stage(0, 0);
    __asm__ volatile("s_waitcnt vmcnt(0)" ::: "memory");
    __builtin_amdgcn_s_barrier();
    __builtin_amdgcn_sched_barrier(0);

    for (int kt = 0; kt < HDIM / 64; ++kt) {
        const int cur = kt & 1, nxt = cur ^ 1;
        if (kt + 1 < HDIM / 64) stage(kt + 1, nxt);   // prefetch under compute
#pragma unroll
        for (int kk = 0; kk < 2; ++kk) {
            const int cb = ((quad << 4) | (kk << 6)) ^ swz;
            half8 af[2], bf[2];
#pragma unroll
            for (int mb = 0; mb < 2; ++mb)
                af[mb] = *(const half8*)((const char*)&Ash[cur][wr + mb * 16 + l16][0] + cb);
#pragma unroll
            for (int nb = 0; nb < 2; ++nb)
                bf[nb] = *(const half8*)((const char*)&Bsh[cur][wc + nb * 16 + l16][0] + cb);
#pragma unroll
            for (int mb = 0; mb < 2; ++mb)
#pragma unroll
                for (int nb = 0; nb < 2; ++nb)
                    acc[mb][nb] = __builtin_amdgcn_mfma_f32_16x16x32_f16(af[mb], bf[nb], acc[mb][nb], 0, 0, 0);
        }
        __asm__ volatile("s_waitcnt vmcnt(0)" ::: "memory");  // next tile landed
        __builtin_amdgcn_s_barrier();
        __builtin_amdgcn_sched_barrier(0);
    }

#pragma unroll
    for (int mb = 0; mb < 2; ++mb)
#pragma unroll
        for (int nb = 0; nb < 2; ++nb) {
            int row0 = bm * 64 + wr + mb * 16 + quad * 4;
            int col  = bn * 64 + wc + nb * 16 + l16;
#pragma unroll
            for (int r = 0; r < 4; ++r)
                outF[(size_t)(row0 + r) * HDIM + col] = acc[mb][nb][r];
        }
}

// ---------------- fused attention ----------------
// Reference semantics: softmax over ALL keys, THEN causal zeroing, NO renorm.
// v6: software-pipelined iteration = { QK(t+1) MFMA ; PV(t) MFMA (independent
// of this iter's exp -> overlaps QK's MFMA->VALU latency) ; exp(t+1)+cvt }.
// K ring depth 3: K(t+3) staged at iter t; invariant at iter top: K(t),K(t+1)
// landed, K(t+2) in flight (end-of-iter vmcnt(1)). pf double-state via
// unroll-by-2 with named arrays (no dynamic indexing). V double-buffer + V
// chunk-swizzle kept from r5.
__global__ __launch_bounds__(512, 4)
void attn_fused(const half_t* __restrict__ Qb, const half_t* __restrict__ Kb,
                const half_t* __restrict__ Vtb, half_t* __restrict__ AOut)
{
    const int bx = blockIdx.x;   // 0..15
    const int p  = bx >> 1;      // q-tile pair (p, 15-p), p in 0..7
    const int hf = bx & 1;       // which 64-row half of each tile
    const int bh = blockIdx.y;   // 0..31 (b*16+h)
    const int NT = SEQ / 64;     // 32

    __shared__ __align__(16) half_t Ksh[3][64][64];   // ring, chunk-swizzled src
    __shared__ __align__(16) half_t Vsh[2][64][64];   // [buf][d][key], chunk-swizzled

    const int t = threadIdx.x;
    const int wave = t >> 6, lane = t & 63, quad = lane >> 4, l16 = lane & 15;
    const int heavy = wave >> 2, wl = wave & 3;
    const int qtile = heavy ? (15 - p) : p;
    const int q0 = qtile * 128 + hf * 64 + wl * 16;   // wave's 16 q rows
    const int ktop = 2 * (15 - p) + hf;               // V staging bound

    // Q fragment (B-operand layout of 16x16x32)
    const half_t* Qp = Qb + ((size_t)bh * SEQ + q0 + l16) * DH + quad * 8;
    const half8 qf0 = *(const half8*)Qp;
    const half8 qf1 = *(const half8*)(Qp + 32);

    float4v o[4] = {};     // O^T accum
    float4v ls = {};       // 4 independent denominator chains

    // K DMA staging: wave stages rows wave*8 .. wave*8+7 (XOR chunk swizzle)
    const int krow = lane >> 3, kpos = lane & 7;
    const int kchunk = kpos ^ krow;
    const half_t* Ksrc = Kb + ((size_t)bh * SEQ + wave * 8 + krow) * DH + kchunk * 8;
    const int ko1 = ((quad ^ (l16 & 7)) * 8);
    const int ko2 = ko1 ^ 32;

    // V staging: 512 threads x 1 uint4 = 64x64 tile; chunk-swizzled store
    const int sr  = t >> 3;                     // 0..63 (d)
    const int svc = ((t & 7) ^ (sr & 7)) * 8;   // swizzled chunk (halves)
    const half_t* Vg = Vtb + ((size_t)bh * DH + sr) * SEQ + (t & 7) * 8;
    const int vxo = l16 & 7;                    // read-side row XOR
    const int vro = (quad & 1) * 8;             // byte offset within 16B chunk

    // ---- prologue: V(0) + K(0),K(1),K(2) ----
    {
        uint4 va = *(const uint4*)(Vg);                       // va FIRST (vm order!)
        glds16(Ksrc,                       &Ksh[0][wave * 8][0]);
        glds16(Ksrc + (size_t)64 * DH,     &Ksh[1][wave * 8][0]);
        glds16(Ksrc + (size_t)2 * 64 * DH, &Ksh[2][wave * 8][0]);
        *(uint4*)&Vsh[0][sr][svc] = va;                       // compiler waits va only
    }
    __asm__ volatile("s_waitcnt vmcnt(1)" ::: "memory");      // K0,K1 done; K2 flying
    __asm__ volatile("s_waitcnt lgkmcnt(0)" ::: "memory");
    __builtin_amdgcn_s_barrier();
    __builtin_amdgcn_sched_barrier(0);

    // ---- pre-compute QK(0) -> pfA (tile 0 is active for every wave) ----
    half4 pfA[4], pfB[4];
    {
        float4v sc[4];
#pragma unroll
        for (int nb = 0; nb < 4; ++nb) {
            const half_t* kp = &Ksh[0][nb * 16 + l16][0];
            half8 kf0 = *(const half8*)(kp + ko1);
            half8 kf1 = *(const half8*)(kp + ko2);
            float4v a = {};
            a = __builtin_amdgcn_mfma_f32_16x16x32_f16(kf0, qf0, a, 0, 0, 0);
            a = __builtin_amdgcn_mfma_f32_16x16x32_f16(kf1, qf1, a, 0, 0, 0);
            sc[nb] = a;
        }
#pragma unroll
        for (int nb = 0; nb < 4; ++nb)
#pragma unroll
            for (int r = 0; r < 4; ++r) {
                float e = __builtin_amdgcn_exp2f(sc[nb][r]);
                sc[nb][r] = e;
                ls[r] += e;
            }
        if (63 > q0) {   // straddle of tile 0
            int qg = q0 + l16;
#pragma unroll
            for (int nb = 0; nb < 4; ++nb)
#pragma unroll
                for (int r = 0; r < 4; ++r)
                    if (nb * 16 + quad * 4 + r > qg) sc[nb][r] = 0.f;
        }
#pragma unroll
        for (int nb = 0; nb < 4; ++nb) {
            union { fp16x2 v2[2]; half4 v4; } u;
            u.v2[0] = __builtin_amdgcn_cvt_pkrtz(sc[nb][0], sc[nb][1]);
            u.v2[1] = __builtin_amdgcn_cvt_pkrtz(sc[nb][2], sc[nb][3]);
            pfA[nb] = u.v4;
        }
    }
    __builtin_amdgcn_s_barrier();   // slot-0 ds_reads done before iter0's K3 DMA
    __builtin_amdgcn_sched_barrier(0);

    int a0 = 0, a1 = 1, a2 = 2;     // a0 = slot of K(t); a1 = slot of K(t+1)

    auto iter = [&](int tk, half4 (&pfP)[4], half4 (&pfC)[4]) {
        const bool vnext = (tk + 1 <= ktop) && (tk + 1 < NT);
        const bool k3    = (tk + 3 < NT);
        const int curv = tk & 1, nxtv = curv ^ 1;

        uint4 van;
        if (vnext) van = *(const uint4*)(Vg + (tk + 1) * 64);   // va FIRST
        if (k3)
            glds16(Ksrc + (size_t)(tk + 3) * 64 * DH, &Ksh[a0][wave * 8][0]);

        // QK(t+1) from slot a1
        const bool qk = (tk + 1 < NT);
        float4v sc[4];
        if (qk) {
            __builtin_amdgcn_s_setprio(1);
#pragma unroll
            for (int nb = 0; nb < 4; ++nb) {
                const half_t* kp = &Ksh[a1][nb * 16 + l16][0];
                half8 kf0 = *(const half8*)(kp + ko1);
                half8 kf1 = *(const half8*)(kp + ko2);
                float4v a = {};
                a = __builtin_amdgcn_mfma_f32_16x16x32_f16(kf0, qf0, a, 0, 0, 0);
                a = __builtin_amdgcn_mfma_f32_16x16x32_f16(kf1, qf1, a, 0, 0, 0);
                sc[nb] = a;
            }
            __builtin_amdgcn_s_setprio(0);
        }

        // PV(t) with pfP — independent of this iteration's exp
        if (tk * 64 <= q0 + 15) {
            __builtin_amdgcn_s_setprio(1);
#pragma unroll
            for (int md = 0; md < 4; ++md) {
                const char* vrow = (const char*)&Vsh[curv][md * 16 + l16][0];
#pragma unroll
                for (int nb = 0; nb < 4; ++nb) {
                    const int sco = (((nb * 2 + (quad >> 1)) ^ vxo) << 4) + vro;
                    half4 vf = *(const half4*)(vrow + sco);
                    o[md] = __builtin_amdgcn_mfma_f32_16x16x16f16(vf, pfP[nb], o[md], 0, 0, 0);
                }
            }
            __builtin_amdgcn_s_setprio(0);
        }

        // exp(t+1) + denominator + mask + cvt -> pfC
        if (qk) {
#pragma unroll
            for (int nb = 0; nb < 4; ++nb)
#pragma unroll
                for (int r = 0; r < 4; ++r) {
                    float e = __builtin_amdgcn_exp2f(sc[nb][r]);
                    sc[nb][r] = e;
                    ls[r] += e;
                }
            const int kbase = (tk + 1) * 64;
            if (kbase <= q0 + 15) {
                if (kbase + 63 > q0) {
                    int qg = q0 + l16;
#pragma unroll
                    for (int nb = 0; nb < 4; ++nb)
#pragma unroll
                        for (int r = 0; r < 4; ++r)
                            if (kbase + nb * 16 + quad * 4 + r > qg) sc[nb][r] = 0.f;
                }
#pragma unroll
                for (int nb = 0; nb < 4; ++nb) {
                    union { fp16x2 v2[2]; half4 v4; } u;
                    u.v2[0] = __builtin_amdgcn_cvt_pkrtz(sc[nb][0], sc[nb][1]);
                    u.v2[1] = __builtin_amdgcn_cvt_pkrtz(sc[nb][2], sc[nb][3]);
                    pfC[nb] = u.v4;
                }
            }
        }

        if (vnext) *(uint4*)&Vsh[nxtv][sr][svc] = van;   // compiler waits van only
        if (k3) { __asm__ volatile("s_waitcnt vmcnt(1)" ::: "memory"); }
        else    { __asm__ volatile("s_waitcnt vmcnt(0)" ::: "memory"); }
        __asm__ volatile("s_waitcnt lgkmcnt(0)" ::: "memory");
        __builtin_amdgcn_s_barrier();
        __builtin_amdgcn_sched_barrier(0);
        const int tmp = a0; a0 = a1; a1 = a2; a2 = tmp;   // rotate ring
    };

    for (int tk = 0; tk < NT; tk += 2) {
        iter(tk,     pfA, pfB);
        iter(tk + 1, pfB, pfA);
    }

    // epilogue: denominator (2 shuffles) + O^T transpose via per-wave LDS scratch.
    const int b = bh >> 4, h = bh & 15;
    const int orow = lane >> 2, occ = (lane & 3) * 16;
    half_t* scr = (heavy ? (half_t*)Vsh : (half_t*)Ksh) + wl * 1152;
    half_t (*Osh)[72] = (half_t(*)[72])scr;   // 16 x 72
    {
        float rs = (ls[0] + ls[1]) + (ls[2] + ls[3]);
        rs += __shfl_xor(rs, 16, 64);
        rs += __shfl_xor(rs, 32, 64);
        const float inv = 1.0f / rs;
#pragma unroll
        for (int md = 0; md < 4; ++md)
#pragma unroll
            for (int r = 0; r < 4; ++r)
                Osh[l16][md * 16 + quad * 4 + r] = (half_t)(o[md][r] * inv);
        __asm__ volatile("s_waitcnt lgkmcnt(0)" ::: "memory");
        uint4 o0 = *(const uint4*)&Osh[orow][occ];
        uint4 o1 = *(const uint4*)&Osh[orow][occ + 8];
        const int s = q0 + orow;
        half_t* dst = AOut + ((size_t)(b * SEQ + s)) * HDIM + h * DH + occ;
        *(uint4*)dst       = o0;
        *(uint4*)(dst + 8) = o1;
    }
}

// ---------------- launch ----------------
extern "C" void kernel_launch(void* const* d_in, const int* in_sizes, int n_in,
                              void* d_out, int out_size, void* d_ws, size_t ws_size,
                              hipStream_t stream)
{
    const float* x  = (const float*)d_in[0];
    const float* wq = (const float*)d_in[1];
    const float* wk = (const float*)d_in[2];
    const float* wv = (const float*)d_in[3];
    const float* wo = (const float*)d_in[4];
    float* out = (float*)d_out;

    char* ws = (char*)d_ws;
    size_t off = 0;
    auto alloc = [&](size_t bytes) -> void* {
        void* p = ws + off;
        off += (bytes + 255) & ~(size_t)255;
        return p;
    };
    half_t* xh   = (half_t*)alloc((size_t)MTOT * HDIM * 2);   // 8 MB
    half_t* wqh  = (half_t*)alloc((size_t)HDIM * HDIM * 2);   // 2 MB
    half_t* wkh  = (half_t*)alloc((size_t)HDIM * HDIM * 2);
    half_t* wvh  = (half_t*)alloc((size_t)HDIM * HDIM * 2);
    half_t* woh  = (half_t*)alloc((size_t)HDIM * HDIM * 2);
    half_t* Qb   = (half_t*)alloc((size_t)BHTOT * SEQ * DH * 2);  // 8 MB
    half_t* Kb   = (half_t*)alloc((size_t)BHTOT * SEQ * DH * 2);
    half_t* Vtb  = (half_t*)alloc((size_t)BHTOT * SEQ * DH * 2);
    half_t* ah   = (half_t*)alloc((size_t)MTOT * HDIM * 2);       // 8 MB
    float2* rope = (float2*)alloc((size_t)SEQ * 32 * sizeof(float2));

    prep<<<8448, 256, 0, stream>>>(x, wq, wk, wv, wo, xh, wqh, wkh, wvh, woh, rope);

    // Q, K, V in one launch (grid.z selects weight + epilogue)
    gemm_qkv<<<dim3(32, 8, 3), 256, 0, stream>>>(xh, wqh, wkh, wvh,
                                                 Qb, Kb, Vtb, rope);
    // attn: 512-thread blocks, 512 blocks = 2 blocks/CU, software-pipelined
    attn_fused<<<dim3(16, 32), 512, 0, stream>>>(Qb, Kb, Vtb, ah);
    // out = attn @ w_o^T: 64x64 tiles, 1024 blocks = 4 blocks/CU, 2-phase
    gemm_out<<<dim3(64, 16), 256, 0, stream>>>(ah, woh, out);
}